// Round 16
// baseline (97.038 us; speedup 1.0000x reference)
//
#include <hip/hip_runtime.h>
#include <math.h>

// VideoPrismAttention: B=4, T=1024, D=1024, N=16, H=64
#define M_TOT 4096          // B*T
#define D_DIM 1024
#define NH    1024          // N*H
#define N3    3072          // fused q|k|v cols
#define T_DIM 1024

typedef __attribute__((ext_vector_type(8))) short bf16x8;
typedef __attribute__((ext_vector_type(4))) float f32x4;
typedef unsigned short u16;
typedef unsigned int   u32;

__device__ __forceinline__ u16 f2bf(float f) {
    u32 u = __float_as_uint(f);
    u32 r = (u + 0x7fffu + ((u >> 16) & 1u)) >> 16;   // RNE
    return (u16)r;
}

// async global->LDS, 16B per lane; dst is wave-uniform base + lane*16
__device__ __forceinline__ void gload16(const void* g, void* l) {
    __builtin_amdgcn_global_load_lds(
        (__attribute__((address_space(1))) void*)g,
        (__attribute__((address_space(3))) void*)l, 16, 0, 0);
}

// ---------------------------------------------------------------------------
// merged cast kernel: blocks [0, 8192) cast query/value f32->bf16;
// blocks [8192, 9216) transpose+cast the 4 weight matrices.
// ---------------------------------------------------------------------------
__global__ __launch_bounds__(256) void cast_all_kernel(
    const float* __restrict__ query, const float* __restrict__ value,
    const float* __restrict__ Wq, const float* __restrict__ Wk,
    const float* __restrict__ Wv, const float* __restrict__ Wo,
    u16* __restrict__ xb, u16* __restrict__ wbT, u16* __restrict__ woT)
{
    const int blk = blockIdx.x;
    const int tid = threadIdx.x;
    if (blk < 8192) {
        const int z = blk >> 12;
        const float* __restrict__ src = z ? value : query;
        u16* dst = xb + (size_t)z * M_TOT * D_DIM;
        const size_t i4 = (size_t)(blk & 4095) * 256 + tid;
        float4 v = *reinterpret_cast<const float4*>(src + i4 * 4);
        ushort4 o;
        o.x = f2bf(v.x); o.y = f2bf(v.y); o.z = f2bf(v.z); o.w = f2bf(v.w);
        *reinterpret_cast<ushort4*>(dst + i4 * 4) = o;
        return;
    }
    const int idx = blk - 8192;            // 0..1023
    const int z = idx >> 8;                // 0..3
    const int bx = idx & 15, by = (idx >> 4) & 15;
    const float* __restrict__ src = (z == 0) ? Wq : (z == 1) ? Wk : (z == 2) ? Wv : Wo;
    u16* dst = (z < 3) ? (wbT + (size_t)z * 1024 * 1024) : woT;
    __shared__ float ts[64][65];
    const int tx = tid & 15, ty = tid >> 4;
    const int c0 = bx * 64, d0 = by * 64;
    #pragma unroll
    for (int i = 0; i < 4; ++i) {
        int r = ty + i * 16;
        float4 v = *reinterpret_cast<const float4*>(&src[(size_t)(d0 + r) * 1024 + c0 + tx * 4]);
        ts[r][tx * 4 + 0] = v.x; ts[r][tx * 4 + 1] = v.y;
        ts[r][tx * 4 + 2] = v.z; ts[r][tx * 4 + 3] = v.w;
    }
    __syncthreads();
    #pragma unroll
    for (int i = 0; i < 4; ++i) {
        int r = ty + i * 16;   // c-local
        ushort4 o;
        o.x = f2bf(ts[tx * 4 + 0][r]);
        o.y = f2bf(ts[tx * 4 + 1][r]);
        o.z = f2bf(ts[tx * 4 + 2][r]);
        o.w = f2bf(ts[tx * 4 + 3][r]);
        *reinterpret_cast<ushort4*>(&dst[(size_t)(c0 + r) * 1024 + d0 + tx * 4]) = o;
    }
}

// ---------------------------------------------------------------------------
// Fused QKV projection GEMM: NEW 256(M)x128(N) tile, BK=32, 8 waves (4Mx2N,
// 64x64 per wave -> 0.5 LDS-reads/MFMA vs 0.75), 3-buffer 2-deep pipeline,
// counted vmcnt(3), T2 swizzle, T1 XCD swizzle.  grid (24,16)=384.
// cols >= 2048 (v) written TRANSPOSED to vt[bn][h][s].
// ---------------------------------------------------------------------------
__global__ __launch_bounds__(512) void gemm_qkv_kernel(
    const u16* __restrict__ xb, const u16* __restrict__ wbT,
    const float* __restrict__ bq, const float* __restrict__ bk,
    const float* __restrict__ bv, const float* __restrict__ pds,
    u16* __restrict__ qkv, u16* __restrict__ vt)
{
    __shared__ __align__(16) u16 Asl[3][256 * 32];   // [row][k] 64B rows, swizzled
    __shared__ __align__(16) u16 Bsl[3][128 * 32];
    const int tid = threadIdx.x;                     // 0..511
    const int l = tid & 63, w = tid >> 6, g = l >> 4;
    const int wr = w & 3, wc = w >> 2;               // 4(M) x 2(N) wave grid
    // T1 bijective swizzle: grid (24,16) = 384 blocks, 384%8==0
    const int disp = blockIdx.x + blockIdx.y * 24;
    const int logical = (disp & 7) * 48 + (disp >> 3);
    const int n0 = (logical % 24) * 128, m0 = (logical / 24) * 256;
    const u16* __restrict__ A = xb + ((n0 >= 2048) ? (size_t)M_TOT * D_DIM : 0);

    // staging: A sweeps j=0,1 cover rows j*128 + tid/4; B covers rows tid/4.
    // phys 16B slot = tid&3; src k-elem = ((tid&3) ^ ((row>>1)&3))*8.
    // (row>>1)&3 is invariant under row+128, so one skel works for both A sweeps.
    const int srow = tid >> 2;
    const int skel = (((tid & 3) ^ ((srow >> 1) & 3)) * 8);

    f32x4 acc[4][4];
    #pragma unroll
    for (int i = 0; i < 4; ++i)
        #pragma unroll
        for (int j = 0; j < 4; ++j)
            acc[i][j] = (f32x4){0.f, 0.f, 0.f, 0.f};

    auto stage = [&](int buf, int k0) {
        gload16(&A  [(size_t)(m0 + srow      ) * 1024 + k0 + skel], &Asl[buf][       w * 512]);
        gload16(&A  [(size_t)(m0 + srow + 128) * 1024 + k0 + skel], &Asl[buf][4096 + w * 512]);
        gload16(&wbT[(size_t)(n0 + srow      ) * 1024 + k0 + skel], &Bsl[buf][       w * 512]);
    };

    stage(0, 0);
    stage(1, 32);

    int cur = 0;
    for (int t = 0; t < 32; ++t) {
        // per-wave FIFO: outstanding = tile-t (3) + tile-(t+1) (3);
        // vmcnt(3) retires exactly tile t; barrier makes it block-wide.
        if (t < 31) asm volatile("s_waitcnt vmcnt(3)" ::: "memory");
        else        asm volatile("s_waitcnt vmcnt(0)" ::: "memory");
        __builtin_amdgcn_s_barrier();
        __builtin_amdgcn_sched_barrier(0);
        if (t < 30) {
            int nbuf = cur + 2; if (nbuf >= 3) nbuf -= 3;
            stage(nbuf, (t + 2) * 32);
        }
        bf16x8 af[4], bfr[4];
        #pragma unroll
        for (int mf = 0; mf < 4; ++mf) {
            int row = wr * 64 + mf * 16 + (l & 15);
            af[mf] = *(const bf16x8*)((const char*)&Asl[cur][0] + row * 64 +
                      ((g ^ ((row >> 1) & 3)) << 4));
        }
        #pragma unroll
        for (int nf = 0; nf < 4; ++nf) {
            int row = wc * 64 + nf * 16 + (l & 15);
            bfr[nf] = *(const bf16x8*)((const char*)&Bsl[cur][0] + row * 64 +
                      ((g ^ ((row >> 1) & 3)) << 4));
        }
        #pragma unroll
        for (int mf = 0; mf < 4; ++mf)
            #pragma unroll
            for (int nf = 0; nf < 4; ++nf)
                acc[mf][nf] = __builtin_amdgcn_mfma_f32_16x16x32_bf16(
                    af[mf], bfr[nf], acc[mf][nf], 0, 0, 0);
        ++cur; if (cur == 3) cur = 0;
    }

    // epilogue: C frag lane mapping col=l&15, row=(l>>4)*4+reg
    const int colb = n0 + wc * 64;
    const int rowb = m0 + wr * 64 + (l >> 4) * 4;
    #pragma unroll
    for (int nf = 0; nf < 4; ++nf) {
        const int col = colb + nf * 16 + (l & 15);
        float bias, scale = 1.0f;
        if (col < 1024) {
            bias = bq[col];
            float x = pds[col & 63];
            float sp = (x > 20.f) ? x : log1pf(expf(x));
            scale = 0.1803368801f * sp;       // r_softplus_0 / sqrt(64)
        } else if (col < 2048) {
            bias = bk[col - 1024];
        } else {
            bias = bv[col - 2048];
        }
        #pragma unroll
        for (int mf = 0; mf < 4; ++mf) {
            if (col < 2048) {
                #pragma unroll
                for (int r = 0; r < 4; ++r) {
                    int row = rowb + mf * 16 + r;
                    qkv[(size_t)row * N3 + col] = f2bf((acc[mf][nf][r] + bias) * scale);
                }
            } else {
                // transposed v: vt[((b*16+n)*64+h)*1024 + s]
                int b   = rowb >> 10;
                int s0r = (rowb + mf * 16) & 1023;
                int h = col & 63, nhd = (col >> 6) & 15;
                ushort4 o;
                o.x = f2bf(acc[mf][nf][0] + bias);
                o.y = f2bf(acc[mf][nf][1] + bias);
                o.z = f2bf(acc[mf][nf][2] + bias);
                o.w = f2bf(acc[mf][nf][3] + bias);
                *reinterpret_cast<ushort4*>(
                    &vt[(size_t)((b * 16 + nhd) * 64 + h) * 1024 + s0r]) = o;
            }
        }
    }
}

// ---------------------------------------------------------------------------
// Attention (round-9 proven best): swapped-QK^T, 8 waves x 16 q-rows,
// grid (8, 64).  2-buf K/V (syncthreads pipeline), exp2-folded cubic
// softcap, cvt_pk P-pack via wave-private LDS slab, MFMA-ones denominator,
// in-register normalize.
// ---------------------------------------------------------------------------
__global__ __launch_bounds__(512) void attn_mfma_kernel(
    const u16* __restrict__ qkv, const u16* __restrict__ vt,
    u16* __restrict__ ctx)
{
    __shared__ __align__(16) u16 Ks [2][64 * 64];   // [s][h] 128B rows, swizzled
    __shared__ __align__(16) u16 Vts[2][64 * 64];   // [h][s] 128B rows, swizzled
    __shared__ __align__(16) u16 Ps [128 * 64];     // [q][s] wave-private 16-row slabs
    const int tid = threadIdx.x;
    const int l = tid & 63, w = tid >> 6, g = l >> 4;
    // XCD swizzle: grid (8,64) = 512 blocks
    const int disp = blockIdx.x + blockIdx.y * 8;
    const int logical = (disp & 7) * 64 + (disp >> 3);
    const int qt = logical & 7, bn = logical >> 3;
    const int b = bn >> 4, n = bn & 15;
    const int q0 = qt * 128;

    auto stage = [&](int buf, int s0) {
        int srow = w * 8 + (l >> 3);         // s for Ks, h for Vts
        int qb   = (l & 7) * 16;             // physical byte (linear dest)
        int lb   = qb ^ ((srow & 7) << 4);   // logical byte (inverse swizzle)
        gload16(&qkv[(size_t)(b * 1024 + s0 + srow) * N3 + 1024 + n * 64 + (lb >> 1)],
                &Ks[buf][w * 512]);
        gload16(&vt[(size_t)(bn * 64 + srow) * 1024 + s0 + (lb >> 1)],
                &Vts[buf][w * 512]);
    };

    stage(0, 0);

    // Q fragments as B-operand (col=q, k=h), pre-scaled by proj epilogue
    bf16x8 qf[2];
    #pragma unroll
    for (int kh = 0; kh < 2; ++kh) {
        int row = b * 1024 + q0 + w * 16 + (l & 15);
        int col = n * 64 + kh * 32 + g * 8;
        qf[kh] = *(const bf16x8*)&qkv[(size_t)row * N3 + col];
    }

    bf16x8 ones;
    #pragma unroll
    for (int j = 0; j < 8; ++j) ones[j] = (short)0x3F80;   // bf16 1.0

    f32x4 acc[4];
    f32x4 acc_d = (f32x4){0.f, 0.f, 0.f, 0.f};
    #pragma unroll
    for (int nf = 0; nf < 4; ++nf) acc[nf] = (f32x4){0.f, 0.f, 0.f, 0.f};

    char* const psb = (char*)Ps + w * 2048;      // wave-private 16 rows

    const float C1 = 1.44269504f;                // log2(e)
    const float C2 = -1.9235934e-4f;             // -log2(e)/7500

    __syncthreads();

    for (int t = 0; t < 16; ++t) {
        const int cur = t & 1;
        if (t < 15) stage(cur ^ 1, (t + 1) * 64);

        // S^T = K Q^T per wave: [64 s][16 q]
        f32x4 st[4];
        __builtin_amdgcn_s_setprio(1);
        #pragma unroll
        for (int sf = 0; sf < 4; ++sf) {
            int rowk = sf * 16 + (l & 15);
            const char* kbp = (const char*)Ks[cur] + rowk * 128;
            int sw = (rowk & 7) << 4;
            bf16x8 kb0 = *(const bf16x8*)(kbp + ((g * 16 +  0) ^ sw));
            bf16x8 kb1 = *(const bf16x8*)(kbp + ((g * 16 + 64) ^ sw));
            f32x4 z = (f32x4){0.f, 0.f, 0.f, 0.f};
            z = __builtin_amdgcn_mfma_f32_16x16x32_bf16(kb0, qf[0], z, 0, 0, 0);
            z = __builtin_amdgcn_mfma_f32_16x16x32_bf16(kb1, qf[1], z, 0, 0, 0);
            st[sf] = z;
        }
        __builtin_amdgcn_s_setprio(0);

        // cubic softcap folded with log2e:  p = 2^( s * (C1 + s^2*C2) )
        #pragma unroll
        for (int sf = 0; sf < 4; ++sf) {
            float p[4];
            #pragma unroll
            for (int r = 0; r < 4; ++r) {
                float sc = st[sf][r];
                float e = sc * fmaf(sc * sc, C2, C1);
                asm("v_exp_f32 %0, %1" : "=v"(p[r]) : "v"(e));
            }
            int row = l & 15;
            uint2 pk;
            asm("v_cvt_pk_bf16_f32 %0, %1, %2" : "=v"(pk.x) : "v"(p[0]), "v"(p[1]));
            asm("v_cvt_pk_bf16_f32 %0, %1, %2" : "=v"(pk.y) : "v"(p[2]), "v"(p[3]));
            *(uint2*)(psb + row * 128 + ((sf * 32 + g * 8) ^ ((row & 7) << 4))) = pk;
        }
        asm volatile("s_waitcnt lgkmcnt(0)");
        __builtin_amdgcn_sched_barrier(0);

        // ctx += P V ; denominator += P * ones  (same A-frag, ones B-frag)
        __builtin_amdgcn_s_setprio(1);
        #pragma unroll
        for (int ks = 0; ks < 2; ++ks) {
            int row = l & 15;
            bf16x8 pa = *(const bf16x8*)(psb + row * 128 +
                        ((ks * 64 + g * 16) ^ ((row & 7) << 4)));
            acc_d = __builtin_amdgcn_mfma_f32_16x16x32_bf16(pa, ones, acc_d, 0, 0, 0);
            #pragma unroll
            for (int nf = 0; nf < 4; ++nf) {
                int rowv = nf * 16 + (l & 15);
                bf16x8 vb = *(const bf16x8*)((const char*)Vts[cur] + rowv * 128 +
                          ((ks * 64 + g * 16) ^ ((rowv & 7) << 4)));
                acc[nf] = __builtin_amdgcn_mfma_f32_16x16x32_bf16(
                    pa, vb, acc[nf], 0, 0, 0);
            }
        }
        __builtin_amdgcn_s_setprio(0);
        __syncthreads();
    }

    // acc_d row mapping (g*4+r) matches acc's C rows -> in-register normalize
    float inv[4];
    #pragma unroll
    for (int r = 0; r < 4; ++r) inv[r] = 1.0f / acc_d[r];

    #pragma unroll
    for (int nf = 0; nf < 4; ++nf) {
        int col = n * 64 + nf * 16 + (l & 15);
        #pragma unroll
        for (int r = 0; r < 4; ++r) {
            int rl = w * 16 + g * 4 + r;
            ctx[(size_t)(b * 1024 + q0 + rl) * NH + col] = f2bf(acc[nf][r] * inv[r]);
        }
    }
}

// ---------------------------------------------------------------------------
// Output projection: 64x128 tile, BK=32, 8 waves (2x4, 32x32 per wave),
// 3-buffer 2-deep pipeline, uniform vmcnt(1), T2 swizzle.  grid (8,64).
// (round-9 proven)
// ---------------------------------------------------------------------------
__global__ __launch_bounds__(512) void gemm_out_kernel(
    const u16* __restrict__ ctx, const u16* __restrict__ woT,
    const float* __restrict__ bo, float* __restrict__ out)
{
    __shared__ __align__(16) u16 Asl[3][64 * 32];
    __shared__ __align__(16) u16 Bsl[3][128 * 32];
    const int tid = threadIdx.x;
    const int l = tid & 63, w = tid >> 6, g = l >> 4;
    const int wr = w >> 2, wc = w & 3;
    const int disp = blockIdx.x + blockIdx.y * 8;
    const int logical = (disp & 7) * 64 + (disp >> 3);
    const int n0 = (logical & 7) * 128, m0 = (logical >> 3) * 64;

    const int srow = w * 16 + (l >> 2);
    const int skel = (((l & 3) ^ ((srow >> 1) & 3)) * 8);

    f32x4 acc[2][2];
    #pragma unroll
    for (int i = 0; i < 2; ++i)
        #pragma unroll
        for (int j = 0; j < 2; ++j)
            acc[i][j] = (f32x4){0.f, 0.f, 0.f, 0.f};

    auto stage = [&](int buf, int k0) {
        gload16(&woT[(size_t)(n0 + srow) * 1024 + k0 + skel], &Bsl[buf][w * 512]);
        if (w < 4)
            gload16(&ctx[(size_t)(m0 + srow) * 1024 + k0 + skel], &Asl[buf][w * 512]);
    };

    stage(0, 0);
    stage(1, 32);

    int cur = 0;
    for (int t = 0; t < 32; ++t) {
        if (t < 31) asm volatile("s_waitcnt vmcnt(1)" ::: "memory");
        else        asm volatile("s_waitcnt vmcnt(0)" ::: "memory");
        __builtin_amdgcn_s_barrier();
        __builtin_amdgcn_sched_barrier(0);
        if (t < 30) {
            int nbuf = cur + 2; if (nbuf >= 3) nbuf -= 3;
            stage(nbuf, (t + 2) * 32);
        }
        bf16x8 af[2], bfr[2];
        #pragma unroll
        for (int mf = 0; mf < 2; ++mf) {
            int row = wr * 32 + mf * 16 + (l & 15);
            af[mf] = *(const bf16x8*)((const char*)&Asl[cur][0] + row * 64 +
                      ((g ^ ((row >> 1) & 3)) << 4));
        }
        #pragma unroll
        for (int nf = 0; nf < 2; ++nf) {
            int row = wc * 32 + nf * 16 + (l & 15);
            bfr[nf] = *(const bf16x8*)((const char*)&Bsl[cur][0] + row * 64 +
                      ((g ^ ((row >> 1) & 3)) << 4));
        }
        #pragma unroll
        for (int mf = 0; mf < 2; ++mf)
            #pragma unroll
            for (int nf = 0; nf < 2; ++nf)
                acc[mf][nf] = __builtin_amdgcn_mfma_f32_16x16x32_bf16(
                    af[mf], bfr[nf], acc[mf][nf], 0, 0, 0);
        ++cur; if (cur == 3) cur = 0;
    }

    const int colb = n0 + wc * 32;
    const int rowb = m0 + wr * 32 + (l >> 4) * 4;
    #pragma unroll
    for (int nf = 0; nf < 2; ++nf) {
        const int col = colb + nf * 16 + (l & 15);
        const float bias = bo[col];
        #pragma unroll
        for (int mf = 0; mf < 2; ++mf)
            #pragma unroll
            for (int r = 0; r < 4; ++r)
                out[(size_t)(rowb + mf * 16 + r) * 1024 + col] = acc[mf][nf][r] + bias;
    }
}

// ---------------------------------------------------------------------------
extern "C" void kernel_launch(void* const* d_in, const int* in_sizes, int n_in,
                              void* d_out, int out_size, void* d_ws, size_t ws_size,
                              hipStream_t stream) {
    const float* query = (const float*)d_in[0];
    const float* value = (const float*)d_in[1];
    const float* Wq    = (const float*)d_in[2];
    const float* bq    = (const float*)d_in[3];
    const float* Wk    = (const float*)d_in[4];
    const float* bk    = (const float*)d_in[5];
    const float* Wv    = (const float*)d_in[6];
    const float* bv    = (const float*)d_in[7];
    const float* Wo    = (const float*)d_in[8];
    const float* bo    = (const float*)d_in[9];
    const float* pds   = (const float*)d_in[10];
    float* out = (float*)d_out;

    // workspace layout (64 MiB total)
    char* ws = (char*)d_ws;
    u16* xb   = (u16*)(ws);                        // 16 MiB: query|value bf16
    u16* wbT  = (u16*)(ws + (16ull << 20));        //  6 MiB: Wq|Wk|Wv ^T bf16
    u16* woT  = (u16*)(ws + (22ull << 20));        //  2 MiB: Wo^T bf16
    u16* qkv  = (u16*)(ws + (24ull << 20));        // 24 MiB: q|k|(unused v)
    u16* vt   = (u16*)(ws + (48ull << 20));        //  8 MiB: v transposed [bn][h][s]
    u16* ctxb = (u16*)(ws + (56ull << 20));        //  8 MiB: context bf16

    cast_all_kernel<<<dim3(9216), 256, 0, stream>>>(
        query, value, Wq, Wk, Wv, Wo, xb, wbT, woT);
    gemm_qkv_kernel<<<dim3(N3 / 128, M_TOT / 256), 512, 0, stream>>>(
        xb, wbT, bq, bk, bv, pds, qkv, vt);
    attn_mfma_kernel<<<dim3(T_DIM / 128, 64), 512, 0, stream>>>(qkv, vt, ctxb);
    gemm_out_kernel<<<dim3(NH / 128, M_TOT / 64), 512, 0, stream>>>(ctxb, woT, bo, out);
}

// Round 17
// 95.246 us; speedup vs baseline: 1.0188x; 1.0188x over previous
//
#include <hip/hip_runtime.h>
#include <math.h>

// VideoPrismAttention: B=4, T=1024, D=1024, N=16, H=64
#define M_TOT 4096          // B*T
#define D_DIM 1024
#define NH    1024          // N*H
#define N3    3072          // fused q|k|v cols
#define T_DIM 1024

typedef __attribute__((ext_vector_type(8))) short bf16x8;
typedef __attribute__((ext_vector_type(4))) float f32x4;
typedef unsigned short u16;
typedef unsigned int   u32;

__device__ __forceinline__ u16 f2bf(float f) {
    u32 u = __float_as_uint(f);
    u32 r = (u + 0x7fffu + ((u >> 16) & 1u)) >> 16;   // RNE
    return (u16)r;
}

// async global->LDS, 16B per lane; dst is wave-uniform base + lane*16
__device__ __forceinline__ void gload16(const void* g, void* l) {
    __builtin_amdgcn_global_load_lds(
        (__attribute__((address_space(1))) void*)g,
        (__attribute__((address_space(3))) void*)l, 16, 0, 0);
}

// ---------------------------------------------------------------------------
// merged cast kernel: blocks [0, 8192) cast query/value f32->bf16;
// blocks [8192, 9216) transpose+cast the 4 weight matrices.
// ---------------------------------------------------------------------------
__global__ __launch_bounds__(256) void cast_all_kernel(
    const float* __restrict__ query, const float* __restrict__ value,
    const float* __restrict__ Wq, const float* __restrict__ Wk,
    const float* __restrict__ Wv, const float* __restrict__ Wo,
    u16* __restrict__ xb, u16* __restrict__ wbT, u16* __restrict__ woT)
{
    const int blk = blockIdx.x;
    const int tid = threadIdx.x;
    if (blk < 8192) {
        const int z = blk >> 12;
        const float* __restrict__ src = z ? value : query;
        u16* dst = xb + (size_t)z * M_TOT * D_DIM;
        const size_t i4 = (size_t)(blk & 4095) * 256 + tid;
        float4 v = *reinterpret_cast<const float4*>(src + i4 * 4);
        ushort4 o;
        o.x = f2bf(v.x); o.y = f2bf(v.y); o.z = f2bf(v.z); o.w = f2bf(v.w);
        *reinterpret_cast<ushort4*>(dst + i4 * 4) = o;
        return;
    }
    const int idx = blk - 8192;            // 0..1023
    const int z = idx >> 8;                // 0..3
    const int bx = idx & 15, by = (idx >> 4) & 15;
    const float* __restrict__ src = (z == 0) ? Wq : (z == 1) ? Wk : (z == 2) ? Wv : Wo;
    u16* dst = (z < 3) ? (wbT + (size_t)z * 1024 * 1024) : woT;
    __shared__ float ts[64][65];
    const int tx = tid & 15, ty = tid >> 4;
    const int c0 = bx * 64, d0 = by * 64;
    #pragma unroll
    for (int i = 0; i < 4; ++i) {
        int r = ty + i * 16;
        float4 v = *reinterpret_cast<const float4*>(&src[(size_t)(d0 + r) * 1024 + c0 + tx * 4]);
        ts[r][tx * 4 + 0] = v.x; ts[r][tx * 4 + 1] = v.y;
        ts[r][tx * 4 + 2] = v.z; ts[r][tx * 4 + 3] = v.w;
    }
    __syncthreads();
    #pragma unroll
    for (int i = 0; i < 4; ++i) {
        int r = ty + i * 16;   // c-local
        ushort4 o;
        o.x = f2bf(ts[tx * 4 + 0][r]);
        o.y = f2bf(ts[tx * 4 + 1][r]);
        o.z = f2bf(ts[tx * 4 + 2][r]);
        o.w = f2bf(ts[tx * 4 + 3][r]);
        *reinterpret_cast<ushort4*>(&dst[(size_t)(c0 + r) * 1024 + d0 + tx * 4]) = o;
    }
}

// ---------------------------------------------------------------------------
// Fused QKV projection GEMM (round-9 proven best): 128x128 tile, BK=32,
// 8 waves (64x32/wave), 3-buffer 2-deep pipeline, counted vmcnt(2),
// T2 swizzle, T1 XCD swizzle.  cols >= 2048 (v) written transposed to vt.
// ---------------------------------------------------------------------------
__global__ __launch_bounds__(512) void gemm_qkv_kernel(
    const u16* __restrict__ xb, const u16* __restrict__ wbT,
    const float* __restrict__ bq, const float* __restrict__ bk,
    const float* __restrict__ bv, const float* __restrict__ pds,
    u16* __restrict__ qkv, u16* __restrict__ vt)
{
    __shared__ __align__(16) u16 Asl[3][128 * 32];   // [row][k] 64B rows, swizzled
    __shared__ __align__(16) u16 Bsl[3][128 * 32];
    const int tid = threadIdx.x;                     // 0..511
    const int l = tid & 63, w = tid >> 6, g = l >> 4;
    const int wr = w >> 2, wc = w & 3;               // 2 x 4 wave grid
    // XCD-aware bijective swizzle: grid (24,32) = 768 blocks, 768%8==0
    const int disp = blockIdx.x + blockIdx.y * 24;
    const int logical = (disp & 7) * 96 + (disp >> 3);
    const int n0 = (logical % 24) * 128, m0 = (logical / 24) * 128;
    const u16* __restrict__ A = xb + ((n0 >= 2048) ? (size_t)M_TOT * D_DIM : 0);

    const int srow = w * 16 + (l >> 2);
    const int skel = (((l & 3) ^ ((srow >> 1) & 3)) * 8);

    f32x4 acc[4][2];
    #pragma unroll
    for (int i = 0; i < 4; ++i)
        #pragma unroll
        for (int j = 0; j < 2; ++j)
            acc[i][j] = (f32x4){0.f, 0.f, 0.f, 0.f};

    auto stage = [&](int buf, int k0) {
        gload16(&A  [(size_t)(m0 + srow) * 1024 + k0 + skel], &Asl[buf][w * 512]);
        gload16(&wbT[(size_t)(n0 + srow) * 1024 + k0 + skel], &Bsl[buf][w * 512]);
    };

    stage(0, 0);
    stage(1, 32);

    int cur = 0;
    for (int t = 0; t < 32; ++t) {
        if (t < 31) asm volatile("s_waitcnt vmcnt(2)" ::: "memory");
        else        asm volatile("s_waitcnt vmcnt(0)" ::: "memory");
        __builtin_amdgcn_s_barrier();
        __builtin_amdgcn_sched_barrier(0);
        if (t < 30) {
            int nbuf = cur + 2; if (nbuf >= 3) nbuf -= 3;
            stage(nbuf, (t + 2) * 32);
        }
        bf16x8 af[4], bfr[2];
        #pragma unroll
        for (int mf = 0; mf < 4; ++mf) {
            int row = wr * 64 + mf * 16 + (l & 15);
            af[mf] = *(const bf16x8*)((const char*)&Asl[cur][0] + row * 64 +
                      ((g ^ ((row >> 1) & 3)) << 4));
        }
        #pragma unroll
        for (int nf = 0; nf < 2; ++nf) {
            int row = wc * 32 + nf * 16 + (l & 15);
            bfr[nf] = *(const bf16x8*)((const char*)&Bsl[cur][0] + row * 64 +
                      ((g ^ ((row >> 1) & 3)) << 4));
        }
        #pragma unroll
        for (int mf = 0; mf < 4; ++mf)
            #pragma unroll
            for (int nf = 0; nf < 2; ++nf)
                acc[mf][nf] = __builtin_amdgcn_mfma_f32_16x16x32_bf16(
                    af[mf], bfr[nf], acc[mf][nf], 0, 0, 0);
        ++cur; if (cur == 3) cur = 0;
    }

    // epilogue: C frag lane mapping col=l&15, row=(l>>4)*4+reg
    const int colb = n0 + wc * 32;
    const int rowb = m0 + wr * 64 + (l >> 4) * 4;
    #pragma unroll
    for (int nf = 0; nf < 2; ++nf) {
        const int col = colb + nf * 16 + (l & 15);
        float bias, scale = 1.0f;
        if (col < 1024) {
            bias = bq[col];
            float x = pds[col & 63];
            float sp = (x > 20.f) ? x : log1pf(expf(x));
            scale = 0.1803368801f * sp;       // r_softplus_0 / sqrt(64)
        } else if (col < 2048) {
            bias = bk[col - 1024];
        } else {
            bias = bv[col - 2048];
        }
        #pragma unroll
        for (int mf = 0; mf < 4; ++mf) {
            if (col < 2048) {
                #pragma unroll
                for (int r = 0; r < 4; ++r) {
                    int row = rowb + mf * 16 + r;
                    qkv[(size_t)row * N3 + col] = f2bf((acc[mf][nf][r] + bias) * scale);
                }
            } else {
                // transposed v: vt[((b*16+n)*64+h)*1024 + s]
                int b   = rowb >> 10;
                int s0r = (rowb + mf * 16) & 1023;
                int h = col & 63, nhd = (col >> 6) & 15;
                ushort4 o;
                o.x = f2bf(acc[mf][nf][0] + bias);
                o.y = f2bf(acc[mf][nf][1] + bias);
                o.z = f2bf(acc[mf][nf][2] + bias);
                o.w = f2bf(acc[mf][nf][3] + bias);
                *reinterpret_cast<ushort4*>(
                    &vt[(size_t)((b * 16 + nhd) * 64 + h) * 1024 + s0r]) = o;
            }
        }
    }
}

// ---------------------------------------------------------------------------
// Attention (round-9 proven best): swapped-QK^T, 8 waves x 16 q-rows,
// grid (8, 64).  2-buf K/V (syncthreads pipeline), exp2-folded cubic
// softcap, cvt_pk P-pack via wave-private LDS slab, MFMA-ones denominator,
// in-register normalize.
// ---------------------------------------------------------------------------
__global__ __launch_bounds__(512) void attn_mfma_kernel(
    const u16* __restrict__ qkv, const u16* __restrict__ vt,
    u16* __restrict__ ctx)
{
    __shared__ __align__(16) u16 Ks [2][64 * 64];   // [s][h] 128B rows, swizzled
    __shared__ __align__(16) u16 Vts[2][64 * 64];   // [h][s] 128B rows, swizzled
    __shared__ __align__(16) u16 Ps [128 * 64];     // [q][s] wave-private 16-row slabs
    const int tid = threadIdx.x;
    const int l = tid & 63, w = tid >> 6, g = l >> 4;
    // XCD swizzle: grid (8,64) = 512 blocks
    const int disp = blockIdx.x + blockIdx.y * 8;
    const int logical = (disp & 7) * 64 + (disp >> 3);
    const int qt = logical & 7, bn = logical >> 3;
    const int b = bn >> 4, n = bn & 15;
    const int q0 = qt * 128;

    auto stage = [&](int buf, int s0) {
        int srow = w * 8 + (l >> 3);         // s for Ks, h for Vts
        int qb   = (l & 7) * 16;             // physical byte (linear dest)
        int lb   = qb ^ ((srow & 7) << 4);   // logical byte (inverse swizzle)
        gload16(&qkv[(size_t)(b * 1024 + s0 + srow) * N3 + 1024 + n * 64 + (lb >> 1)],
                &Ks[buf][w * 512]);
        gload16(&vt[(size_t)(bn * 64 + srow) * 1024 + s0 + (lb >> 1)],
                &Vts[buf][w * 512]);
    };

    stage(0, 0);

    // Q fragments as B-operand (col=q, k=h), pre-scaled by proj epilogue
    bf16x8 qf[2];
    #pragma unroll
    for (int kh = 0; kh < 2; ++kh) {
        int row = b * 1024 + q0 + w * 16 + (l & 15);
        int col = n * 64 + kh * 32 + g * 8;
        qf[kh] = *(const bf16x8*)&qkv[(size_t)row * N3 + col];
    }

    bf16x8 ones;
    #pragma unroll
    for (int j = 0; j < 8; ++j) ones[j] = (short)0x3F80;   // bf16 1.0

    f32x4 acc[4];
    f32x4 acc_d = (f32x4){0.f, 0.f, 0.f, 0.f};
    #pragma unroll
    for (int nf = 0; nf < 4; ++nf) acc[nf] = (f32x4){0.f, 0.f, 0.f, 0.f};

    char* const psb = (char*)Ps + w * 2048;      // wave-private 16 rows

    const float C1 = 1.44269504f;                // log2(e)
    const float C2 = -1.9235934e-4f;             // -log2(e)/7500

    __syncthreads();

    for (int t = 0; t < 16; ++t) {
        const int cur = t & 1;
        if (t < 15) stage(cur ^ 1, (t + 1) * 64);

        // S^T = K Q^T per wave: [64 s][16 q]
        f32x4 st[4];
        __builtin_amdgcn_s_setprio(1);
        #pragma unroll
        for (int sf = 0; sf < 4; ++sf) {
            int rowk = sf * 16 + (l & 15);
            const char* kbp = (const char*)Ks[cur] + rowk * 128;
            int sw = (rowk & 7) << 4;
            bf16x8 kb0 = *(const bf16x8*)(kbp + ((g * 16 +  0) ^ sw));
            bf16x8 kb1 = *(const bf16x8*)(kbp + ((g * 16 + 64) ^ sw));
            f32x4 z = (f32x4){0.f, 0.f, 0.f, 0.f};
            z = __builtin_amdgcn_mfma_f32_16x16x32_bf16(kb0, qf[0], z, 0, 0, 0);
            z = __builtin_amdgcn_mfma_f32_16x16x32_bf16(kb1, qf[1], z, 0, 0, 0);
            st[sf] = z;
        }
        __builtin_amdgcn_s_setprio(0);

        // cubic softcap folded with log2e:  p = 2^( s * (C1 + s^2*C2) )
        #pragma unroll
        for (int sf = 0; sf < 4; ++sf) {
            float p[4];
            #pragma unroll
            for (int r = 0; r < 4; ++r) {
                float sc = st[sf][r];
                float e = sc * fmaf(sc * sc, C2, C1);
                asm("v_exp_f32 %0, %1" : "=v"(p[r]) : "v"(e));
            }
            int row = l & 15;
            uint2 pk;
            asm("v_cvt_pk_bf16_f32 %0, %1, %2" : "=v"(pk.x) : "v"(p[0]), "v"(p[1]));
            asm("v_cvt_pk_bf16_f32 %0, %1, %2" : "=v"(pk.y) : "v"(p[2]), "v"(p[3]));
            *(uint2*)(psb + row * 128 + ((sf * 32 + g * 8) ^ ((row & 7) << 4))) = pk;
        }
        asm volatile("s_waitcnt lgkmcnt(0)");
        __builtin_amdgcn_sched_barrier(0);

        // ctx += P V ; denominator += P * ones  (same A-frag, ones B-frag)
        __builtin_amdgcn_s_setprio(1);
        #pragma unroll
        for (int ks = 0; ks < 2; ++ks) {
            int row = l & 15;
            bf16x8 pa = *(const bf16x8*)(psb + row * 128 +
                        ((ks * 64 + g * 16) ^ ((row & 7) << 4)));
            acc_d = __builtin_amdgcn_mfma_f32_16x16x32_bf16(pa, ones, acc_d, 0, 0, 0);
            #pragma unroll
            for (int nf = 0; nf < 4; ++nf) {
                int rowv = nf * 16 + (l & 15);
                bf16x8 vb = *(const bf16x8*)((const char*)Vts[cur] + rowv * 128 +
                          ((ks * 64 + g * 16) ^ ((rowv & 7) << 4)));
                acc[nf] = __builtin_amdgcn_mfma_f32_16x16x32_bf16(
                    pa, vb, acc[nf], 0, 0, 0);
            }
        }
        __builtin_amdgcn_s_setprio(0);
        __syncthreads();
    }

    // acc_d row mapping (g*4+r) matches acc's C rows -> in-register normalize
    float inv[4];
    #pragma unroll
    for (int r = 0; r < 4; ++r) inv[r] = 1.0f / acc_d[r];

    #pragma unroll
    for (int nf = 0; nf < 4; ++nf) {
        int col = n * 64 + nf * 16 + (l & 15);
        #pragma unroll
        for (int r = 0; r < 4; ++r) {
            int rl = w * 16 + g * 4 + r;
            ctx[(size_t)(b * 1024 + q0 + rl) * NH + col] = f2bf(acc[nf][r] * inv[r]);
        }
    }
}

// ---------------------------------------------------------------------------
// Output projection: 64x128 tile, BK=32, 8 waves (2x4, 32x32 per wave),
// 3-buffer 2-deep pipeline, uniform vmcnt(1), T2 swizzle.  grid (8,64).
// (round-9 proven)
// ---------------------------------------------------------------------------
__global__ __launch_bounds__(512) void gemm_out_kernel(
    const u16* __restrict__ ctx, const u16* __restrict__ woT,
    const float* __restrict__ bo, float* __restrict__ out)
{
    __shared__ __align__(16) u16 Asl[3][64 * 32];
    __shared__ __align__(16) u16 Bsl[3][128 * 32];
    const int tid = threadIdx.x;
    const int l = tid & 63, w = tid >> 6, g = l >> 4;
    const int wr = w >> 2, wc = w & 3;
    const int disp = blockIdx.x + blockIdx.y * 8;
    const int logical = (disp & 7) * 64 + (disp >> 3);
    const int n0 = (logical & 7) * 128, m0 = (logical >> 3) * 64;

    const int srow = w * 16 + (l >> 2);
    const int skel = (((l & 3) ^ ((srow >> 1) & 3)) * 8);

    f32x4 acc[2][2];
    #pragma unroll
    for (int i = 0; i < 2; ++i)
        #pragma unroll
        for (int j = 0; j < 2; ++j)
            acc[i][j] = (f32x4){0.f, 0.f, 0.f, 0.f};

    auto stage = [&](int buf, int k0) {
        gload16(&woT[(size_t)(n0 + srow) * 1024 + k0 + skel], &Bsl[buf][w * 512]);
        if (w < 4)
            gload16(&ctx[(size_t)(m0 + srow) * 1024 + k0 + skel], &Asl[buf][w * 512]);
    };

    stage(0, 0);
    stage(1, 32);

    int cur = 0;
    for (int t = 0; t < 32; ++t) {
        if (t < 31) asm volatile("s_waitcnt vmcnt(1)" ::: "memory");
        else        asm volatile("s_waitcnt vmcnt(0)" ::: "memory");
        __builtin_amdgcn_s_barrier();
        __builtin_amdgcn_sched_barrier(0);
        if (t < 30) {
            int nbuf = cur + 2; if (nbuf >= 3) nbuf -= 3;
            stage(nbuf, (t + 2) * 32);
        }
        bf16x8 af[2], bfr[2];
        #pragma unroll
        for (int mf = 0; mf < 2; ++mf) {
            int row = wr * 32 + mf * 16 + (l & 15);
            af[mf] = *(const bf16x8*)((const char*)&Asl[cur][0] + row * 64 +
                      ((g ^ ((row >> 1) & 3)) << 4));
        }
        #pragma unroll
        for (int nf = 0; nf < 2; ++nf) {
            int row = wc * 32 + nf * 16 + (l & 15);
            bfr[nf] = *(const bf16x8*)((const char*)&Bsl[cur][0] + row * 64 +
                      ((g ^ ((row >> 1) & 3)) << 4));
        }
        #pragma unroll
        for (int mf = 0; mf < 2; ++mf)
            #pragma unroll
            for (int nf = 0; nf < 2; ++nf)
                acc[mf][nf] = __builtin_amdgcn_mfma_f32_16x16x32_bf16(
                    af[mf], bfr[nf], acc[mf][nf], 0, 0, 0);
        ++cur; if (cur == 3) cur = 0;
    }

    const int colb = n0 + wc * 32;
    const int rowb = m0 + wr * 32 + (l >> 4) * 4;
    #pragma unroll
    for (int nf = 0; nf < 2; ++nf) {
        const int col = colb + nf * 16 + (l & 15);
        const float bias = bo[col];
        #pragma unroll
        for (int mf = 0; mf < 2; ++mf)
            #pragma unroll
            for (int r = 0; r < 4; ++r)
                out[(size_t)(rowb + mf * 16 + r) * 1024 + col] = acc[mf][nf][r] + bias;
    }
}

// ---------------------------------------------------------------------------
extern "C" void kernel_launch(void* const* d_in, const int* in_sizes, int n_in,
                              void* d_out, int out_size, void* d_ws, size_t ws_size,
                              hipStream_t stream) {
    const float* query = (const float*)d_in[0];
    const float* value = (const float*)d_in[1];
    const float* Wq    = (const float*)d_in[2];
    const float* bq    = (const float*)d_in[3];
    const float* Wk    = (const float*)d_in[4];
    const float* bk    = (const float*)d_in[5];
    const float* Wv    = (const float*)d_in[6];
    const float* bv    = (const float*)d_in[7];
    const float* Wo    = (const float*)d_in[8];
    const float* bo    = (const float*)d_in[9];
    const float* pds   = (const float*)d_in[10];
    float* out = (float*)d_out;

    // workspace layout (64 MiB total)
    char* ws = (char*)d_ws;
    u16* xb   = (u16*)(ws);                        // 16 MiB: query|value bf16
    u16* wbT  = (u16*)(ws + (16ull << 20));        //  6 MiB: Wq|Wk|Wv ^T bf16
    u16* woT  = (u16*)(ws + (22ull << 20));        //  2 MiB: Wo^T bf16
    u16* qkv  = (u16*)(ws + (24ull << 20));        // 24 MiB: q|k|(unused v)
    u16* vt   = (u16*)(ws + (48ull << 20));        //  8 MiB: v transposed [bn][h][s]
    u16* ctxb = (u16*)(ws + (56ull << 20));        //  8 MiB: context bf16

    cast_all_kernel<<<dim3(9216), 256, 0, stream>>>(
        query, value, Wq, Wk, Wv, Wo, xb, wbT, woT);
    gemm_qkv_kernel<<<dim3(N3 / 128, M_TOT / 128), 512, 0, stream>>>(
        xb, wbT, bq, bk, bv, pds, qkv, vt);
    attn_mfma_kernel<<<dim3(T_DIM / 128, 64), 512, 0, stream>>>(qkv, vt, ctxb);
    gemm_out_kernel<<<dim3(NH / 128, M_TOT / 64), 512, 0, stream>>>(ctxb, woT, bo, out);
}

// Round 18
// 95.055 us; speedup vs baseline: 1.0209x; 1.0020x over previous
//
#include <hip/hip_runtime.h>
#include <math.h>

// VideoPrismAttention: B=4, T=1024, D=1024, N=16, H=64
#define M_TOT 4096          // B*T
#define D_DIM 1024
#define NH    1024          // N*H
#define N3    3072          // fused q|k|v cols
#define T_DIM 1024

typedef __attribute__((ext_vector_type(8))) short bf16x8;
typedef __attribute__((ext_vector_type(4))) float f32x4;
typedef unsigned short u16;
typedef unsigned int   u32;

__device__ __forceinline__ u16 f2bf(float f) {
    u32 u = __float_as_uint(f);
    u32 r = (u + 0x7fffu + ((u >> 16) & 1u)) >> 16;   // RNE
    return (u16)r;
}

// async global->LDS, 16B per lane; dst is wave-uniform base + lane*16
__device__ __forceinline__ void gload16(const void* g, void* l) {
    __builtin_amdgcn_global_load_lds(
        (__attribute__((address_space(1))) void*)g,
        (__attribute__((address_space(3))) void*)l, 16, 0, 0);
}

// ---------------------------------------------------------------------------
// merged cast kernel: blocks [0, 8192) cast query/value f32->bf16;
// blocks [8192, 9216) transpose+cast the 4 weight matrices.
// ---------------------------------------------------------------------------
__global__ __launch_bounds__(256) void cast_all_kernel(
    const float* __restrict__ query, const float* __restrict__ value,
    const float* __restrict__ Wq, const float* __restrict__ Wk,
    const float* __restrict__ Wv, const float* __restrict__ Wo,
    u16* __restrict__ xb, u16* __restrict__ wbT, u16* __restrict__ woT)
{
    const int blk = blockIdx.x;
    const int tid = threadIdx.x;
    if (blk < 8192) {
        const int z = blk >> 12;
        const float* __restrict__ src = z ? value : query;
        u16* dst = xb + (size_t)z * M_TOT * D_DIM;
        const size_t i4 = (size_t)(blk & 4095) * 256 + tid;
        float4 v = *reinterpret_cast<const float4*>(src + i4 * 4);
        ushort4 o;
        o.x = f2bf(v.x); o.y = f2bf(v.y); o.z = f2bf(v.z); o.w = f2bf(v.w);
        *reinterpret_cast<ushort4*>(dst + i4 * 4) = o;
        return;
    }
    const int idx = blk - 8192;            // 0..1023
    const int z = idx >> 8;                // 0..3
    const int bx = idx & 15, by = (idx >> 4) & 15;
    const float* __restrict__ src = (z == 0) ? Wq : (z == 1) ? Wk : (z == 2) ? Wv : Wo;
    u16* dst = (z < 3) ? (wbT + (size_t)z * 1024 * 1024) : woT;
    __shared__ float ts[64][65];
    const int tx = tid & 15, ty = tid >> 4;
    const int c0 = bx * 64, d0 = by * 64;
    #pragma unroll
    for (int i = 0; i < 4; ++i) {
        int r = ty + i * 16;
        float4 v = *reinterpret_cast<const float4*>(&src[(size_t)(d0 + r) * 1024 + c0 + tx * 4]);
        ts[r][tx * 4 + 0] = v.x; ts[r][tx * 4 + 1] = v.y;
        ts[r][tx * 4 + 2] = v.z; ts[r][tx * 4 + 3] = v.w;
    }
    __syncthreads();
    #pragma unroll
    for (int i = 0; i < 4; ++i) {
        int r = ty + i * 16;   // c-local
        ushort4 o;
        o.x = f2bf(ts[tx * 4 + 0][r]);
        o.y = f2bf(ts[tx * 4 + 1][r]);
        o.z = f2bf(ts[tx * 4 + 2][r]);
        o.w = f2bf(ts[tx * 4 + 3][r]);
        *reinterpret_cast<ushort4*>(&dst[(size_t)(c0 + r) * 1024 + d0 + tx * 4]) = o;
    }
}

// ---------------------------------------------------------------------------
// Fused QKV projection GEMM (round-9 proven best): 128x128 tile, BK=32,
// 8 waves (64x32/wave), 3-buffer 2-deep pipeline, counted vmcnt(2),
// T2 swizzle, T1 XCD swizzle.  cols >= 2048 (v) written transposed to vt.
// ---------------------------------------------------------------------------
__global__ __launch_bounds__(512) void gemm_qkv_kernel(
    const u16* __restrict__ xb, const u16* __restrict__ wbT,
    const float* __restrict__ bq, const float* __restrict__ bk,
    const float* __restrict__ bv, const float* __restrict__ pds,
    u16* __restrict__ qkv, u16* __restrict__ vt)
{
    __shared__ __align__(16) u16 Asl[3][128 * 32];   // [row][k] 64B rows, swizzled
    __shared__ __align__(16) u16 Bsl[3][128 * 32];
    const int tid = threadIdx.x;                     // 0..511
    const int l = tid & 63, w = tid >> 6, g = l >> 4;
    const int wr = w >> 2, wc = w & 3;               // 2 x 4 wave grid
    // XCD-aware bijective swizzle: grid (24,32) = 768 blocks, 768%8==0
    const int disp = blockIdx.x + blockIdx.y * 24;
    const int logical = (disp & 7) * 96 + (disp >> 3);
    const int n0 = (logical % 24) * 128, m0 = (logical / 24) * 128;
    const u16* __restrict__ A = xb + ((n0 >= 2048) ? (size_t)M_TOT * D_DIM : 0);

    const int srow = w * 16 + (l >> 2);
    const int skel = (((l & 3) ^ ((srow >> 1) & 3)) * 8);

    f32x4 acc[4][2];
    #pragma unroll
    for (int i = 0; i < 4; ++i)
        #pragma unroll
        for (int j = 0; j < 2; ++j)
            acc[i][j] = (f32x4){0.f, 0.f, 0.f, 0.f};

    auto stage = [&](int buf, int k0) {
        gload16(&A  [(size_t)(m0 + srow) * 1024 + k0 + skel], &Asl[buf][w * 512]);
        gload16(&wbT[(size_t)(n0 + srow) * 1024 + k0 + skel], &Bsl[buf][w * 512]);
    };

    stage(0, 0);
    stage(1, 32);

    int cur = 0;
    for (int t = 0; t < 32; ++t) {
        if (t < 31) asm volatile("s_waitcnt vmcnt(2)" ::: "memory");
        else        asm volatile("s_waitcnt vmcnt(0)" ::: "memory");
        __builtin_amdgcn_s_barrier();
        __builtin_amdgcn_sched_barrier(0);
        if (t < 30) {
            int nbuf = cur + 2; if (nbuf >= 3) nbuf -= 3;
            stage(nbuf, (t + 2) * 32);
        }
        bf16x8 af[4], bfr[2];
        #pragma unroll
        for (int mf = 0; mf < 4; ++mf) {
            int row = wr * 64 + mf * 16 + (l & 15);
            af[mf] = *(const bf16x8*)((const char*)&Asl[cur][0] + row * 64 +
                      ((g ^ ((row >> 1) & 3)) << 4));
        }
        #pragma unroll
        for (int nf = 0; nf < 2; ++nf) {
            int row = wc * 32 + nf * 16 + (l & 15);
            bfr[nf] = *(const bf16x8*)((const char*)&Bsl[cur][0] + row * 64 +
                      ((g ^ ((row >> 1) & 3)) << 4));
        }
        #pragma unroll
        for (int mf = 0; mf < 4; ++mf)
            #pragma unroll
            for (int nf = 0; nf < 2; ++nf)
                acc[mf][nf] = __builtin_amdgcn_mfma_f32_16x16x32_bf16(
                    af[mf], bfr[nf], acc[mf][nf], 0, 0, 0);
        ++cur; if (cur == 3) cur = 0;
    }

    // epilogue: C frag lane mapping col=l&15, row=(l>>4)*4+reg
    const int colb = n0 + wc * 32;
    const int rowb = m0 + wr * 64 + (l >> 4) * 4;
    #pragma unroll
    for (int nf = 0; nf < 2; ++nf) {
        const int col = colb + nf * 16 + (l & 15);
        float bias, scale = 1.0f;
        if (col < 1024) {
            bias = bq[col];
            float x = pds[col & 63];
            float sp = (x > 20.f) ? x : log1pf(expf(x));
            scale = 0.1803368801f * sp;       // r_softplus_0 / sqrt(64)
        } else if (col < 2048) {
            bias = bk[col - 1024];
        } else {
            bias = bv[col - 2048];
        }
        #pragma unroll
        for (int mf = 0; mf < 4; ++mf) {
            if (col < 2048) {
                #pragma unroll
                for (int r = 0; r < 4; ++r) {
                    int row = rowb + mf * 16 + r;
                    qkv[(size_t)row * N3 + col] = f2bf((acc[mf][nf][r] + bias) * scale);
                }
            } else {
                // transposed v: vt[((b*16+n)*64+h)*1024 + s]
                int b   = rowb >> 10;
                int s0r = (rowb + mf * 16) & 1023;
                int h = col & 63, nhd = (col >> 6) & 15;
                ushort4 o;
                o.x = f2bf(acc[mf][nf][0] + bias);
                o.y = f2bf(acc[mf][nf][1] + bias);
                o.z = f2bf(acc[mf][nf][2] + bias);
                o.w = f2bf(acc[mf][nf][3] + bias);
                *reinterpret_cast<ushort4*>(
                    &vt[(size_t)((b * 16 + nhd) * 64 + h) * 1024 + s0r]) = o;
            }
        }
    }
}

// ---------------------------------------------------------------------------
// Attention: round-9 structure + 3-buffer counted-vmcnt K/V staging (the
// de-drain fix, isolated).  8 waves x 16 q-rows, grid (8, 64).  Q loaded and
// drained BEFORE the stage FIFO so vmcnt counts stay exact.  P-LDS roundtrip,
// MFMA-ones denominator, cubic softcap — identical to round 9.
// ---------------------------------------------------------------------------
__global__ __launch_bounds__(512) void attn_mfma_kernel(
    const u16* __restrict__ qkv, const u16* __restrict__ vt,
    u16* __restrict__ ctx)
{
    __shared__ __align__(16) u16 Ks [3][64 * 64];   // [s][h] 128B rows, swizzled
    __shared__ __align__(16) u16 Vts[3][64 * 64];   // [h][s] 128B rows, swizzled
    __shared__ __align__(16) u16 Ps [128 * 64];     // [q][s] wave-private 16-row slabs
    const int tid = threadIdx.x;
    const int l = tid & 63, w = tid >> 6, g = l >> 4;
    // XCD swizzle: grid (8,64) = 512 blocks
    const int disp = blockIdx.x + blockIdx.y * 8;
    const int logical = (disp & 7) * 64 + (disp >> 3);
    const int qt = logical & 7, bn = logical >> 3;
    const int b = bn >> 4, n = bn & 15;
    const int q0 = qt * 128;

    // Q fragments as B-operand (col=q, k=h), pre-scaled by proj epilogue.
    // Loaded BEFORE any gload16 + drained, so manual vmcnt counts stay exact.
    bf16x8 qf[2];
    #pragma unroll
    for (int kh = 0; kh < 2; ++kh) {
        int row = b * 1024 + q0 + w * 16 + (l & 15);
        int col = n * 64 + kh * 32 + g * 8;
        qf[kh] = *(const bf16x8*)&qkv[(size_t)row * N3 + col];
    }
    asm volatile("s_waitcnt vmcnt(0)" ::: "memory");
    __builtin_amdgcn_sched_barrier(0);

    auto stage = [&](int buf, int s0) {
        int srow = w * 8 + (l >> 3);         // s for Ks, h for Vts
        int qb   = (l & 7) * 16;             // physical byte (linear dest)
        int lb   = qb ^ ((srow & 7) << 4);   // logical byte (inverse swizzle)
        gload16(&qkv[(size_t)(b * 1024 + s0 + srow) * N3 + 1024 + n * 64 + (lb >> 1)],
                &Ks[buf][w * 512]);
        gload16(&vt[(size_t)(bn * 64 + srow) * 1024 + s0 + (lb >> 1)],
                &Vts[buf][w * 512]);
    };

    stage(0, 0);
    stage(1, 64);

    bf16x8 ones;
    #pragma unroll
    for (int j = 0; j < 8; ++j) ones[j] = (short)0x3F80;   // bf16 1.0

    f32x4 acc[4];
    f32x4 acc_d = (f32x4){0.f, 0.f, 0.f, 0.f};
    #pragma unroll
    for (int nf = 0; nf < 4; ++nf) acc[nf] = (f32x4){0.f, 0.f, 0.f, 0.f};

    char* const psb = (char*)Ps + w * 2048;      // wave-private 16 rows

    const float C1 = 1.44269504f;                // log2(e)
    const float C2 = -1.9235934e-4f;             // -log2(e)/7500

    int cur = 0;
    for (int t = 0; t < 16; ++t) {
        // per-wave FIFO: outstanding = stage(t) (2) + stage(t+1) (2);
        // vmcnt(2) retires exactly stage(t); barrier makes it block-wide.
        if (t < 15) asm volatile("s_waitcnt vmcnt(2)" ::: "memory");
        else        asm volatile("s_waitcnt vmcnt(0)" ::: "memory");
        __builtin_amdgcn_s_barrier();
        __builtin_amdgcn_sched_barrier(0);
        if (t < 14) {
            int nbuf = cur + 2; if (nbuf >= 3) nbuf -= 3;
            stage(nbuf, (t + 2) * 64);
        }

        // S^T = K Q^T per wave: [64 s][16 q]
        f32x4 st[4];
        __builtin_amdgcn_s_setprio(1);
        #pragma unroll
        for (int sf = 0; sf < 4; ++sf) {
            int rowk = sf * 16 + (l & 15);
            const char* kbp = (const char*)Ks[cur] + rowk * 128;
            int sw = (rowk & 7) << 4;
            bf16x8 kb0 = *(const bf16x8*)(kbp + ((g * 16 +  0) ^ sw));
            bf16x8 kb1 = *(const bf16x8*)(kbp + ((g * 16 + 64) ^ sw));
            f32x4 z = (f32x4){0.f, 0.f, 0.f, 0.f};
            z = __builtin_amdgcn_mfma_f32_16x16x32_bf16(kb0, qf[0], z, 0, 0, 0);
            z = __builtin_amdgcn_mfma_f32_16x16x32_bf16(kb1, qf[1], z, 0, 0, 0);
            st[sf] = z;
        }
        __builtin_amdgcn_s_setprio(0);

        // cubic softcap folded with log2e:  p = 2^( s * (C1 + s^2*C2) )
        #pragma unroll
        for (int sf = 0; sf < 4; ++sf) {
            float p[4];
            #pragma unroll
            for (int r = 0; r < 4; ++r) {
                float sc = st[sf][r];
                float e = sc * fmaf(sc * sc, C2, C1);
                asm("v_exp_f32 %0, %1" : "=v"(p[r]) : "v"(e));
            }
            int row = l & 15;
            uint2 pk;
            asm("v_cvt_pk_bf16_f32 %0, %1, %2" : "=v"(pk.x) : "v"(p[0]), "v"(p[1]));
            asm("v_cvt_pk_bf16_f32 %0, %1, %2" : "=v"(pk.y) : "v"(p[2]), "v"(p[3]));
            *(uint2*)(psb + row * 128 + ((sf * 32 + g * 8) ^ ((row & 7) << 4))) = pk;
        }
        asm volatile("s_waitcnt lgkmcnt(0)");
        __builtin_amdgcn_sched_barrier(0);

        // ctx += P V ; denominator += P * ones  (same A-frag, ones B-frag)
        __builtin_amdgcn_s_setprio(1);
        #pragma unroll
        for (int ks = 0; ks < 2; ++ks) {
            int row = l & 15;
            bf16x8 pa = *(const bf16x8*)(psb + row * 128 +
                        ((ks * 64 + g * 16) ^ ((row & 7) << 4)));
            acc_d = __builtin_amdgcn_mfma_f32_16x16x32_bf16(pa, ones, acc_d, 0, 0, 0);
            #pragma unroll
            for (int nf = 0; nf < 4; ++nf) {
                int rowv = nf * 16 + (l & 15);
                bf16x8 vb = *(const bf16x8*)((const char*)Vts[cur] + rowv * 128 +
                          ((ks * 64 + g * 16) ^ ((rowv & 7) << 4)));
                acc[nf] = __builtin_amdgcn_mfma_f32_16x16x32_bf16(
                    pa, vb, acc[nf], 0, 0, 0);
            }
        }
        __builtin_amdgcn_s_setprio(0);
        ++cur; if (cur == 3) cur = 0;
    }

    // acc_d row mapping (g*4+r) matches acc's C rows -> in-register normalize
    float inv[4];
    #pragma unroll
    for (int r = 0; r < 4; ++r) inv[r] = 1.0f / acc_d[r];

    #pragma unroll
    for (int nf = 0; nf < 4; ++nf) {
        int col = n * 64 + nf * 16 + (l & 15);
        #pragma unroll
        for (int r = 0; r < 4; ++r) {
            int rl = w * 16 + g * 4 + r;
            ctx[(size_t)(b * 1024 + q0 + rl) * NH + col] = f2bf(acc[nf][r] * inv[r]);
        }
    }
}

// ---------------------------------------------------------------------------
// Output projection: 64x128 tile, BK=32, 8 waves (2x4, 32x32 per wave),
// 3-buffer 2-deep pipeline, uniform vmcnt(1), T2 swizzle.  grid (8,64).
// (round-9 proven)
// ---------------------------------------------------------------------------
__global__ __launch_bounds__(512) void gemm_out_kernel(
    const u16* __restrict__ ctx, const u16* __restrict__ woT,
    const float* __restrict__ bo, float* __restrict__ out)
{
    __shared__ __align__(16) u16 Asl[3][64 * 32];
    __shared__ __align__(16) u16 Bsl[3][128 * 32];
    const int tid = threadIdx.x;
    const int l = tid & 63, w = tid >> 6, g = l >> 4;
    const int wr = w >> 2, wc = w & 3;
    const int disp = blockIdx.x + blockIdx.y * 8;
    const int logical = (disp & 7) * 64 + (disp >> 3);
    const int n0 = (logical & 7) * 128, m0 = (logical >> 3) * 64;

    const int srow = w * 16 + (l >> 2);
    const int skel = (((l & 3) ^ ((srow >> 1) & 3)) * 8);

    f32x4 acc[2][2];
    #pragma unroll
    for (int i = 0; i < 2; ++i)
        #pragma unroll
        for (int j = 0; j < 2; ++j)
            acc[i][j] = (f32x4){0.f, 0.f, 0.f, 0.f};

    auto stage = [&](int buf, int k0) {
        gload16(&woT[(size_t)(n0 + srow) * 1024 + k0 + skel], &Bsl[buf][w * 512]);
        if (w < 4)
            gload16(&ctx[(size_t)(m0 + srow) * 1024 + k0 + skel], &Asl[buf][w * 512]);
    };

    stage(0, 0);
    stage(1, 32);

    int cur = 0;
    for (int t = 0; t < 32; ++t) {
        if (t < 31) asm volatile("s_waitcnt vmcnt(1)" ::: "memory");
        else        asm volatile("s_waitcnt vmcnt(0)" ::: "memory");
        __builtin_amdgcn_s_barrier();
        __builtin_amdgcn_sched_barrier(0);
        if (t < 30) {
            int nbuf = cur + 2; if (nbuf >= 3) nbuf -= 3;
            stage(nbuf, (t + 2) * 32);
        }
        bf16x8 af[2], bfr[2];
        #pragma unroll
        for (int mf = 0; mf < 2; ++mf) {
            int row = wr * 32 + mf * 16 + (l & 15);
            af[mf] = *(const bf16x8*)((const char*)&Asl[cur][0] + row * 64 +
                      ((g ^ ((row >> 1) & 3)) << 4));
        }
        #pragma unroll
        for (int nf = 0; nf < 2; ++nf) {
            int row = wc * 32 + nf * 16 + (l & 15);
            bfr[nf] = *(const bf16x8*)((const char*)&Bsl[cur][0] + row * 64 +
                      ((g ^ ((row >> 1) & 3)) << 4));
        }
        #pragma unroll
        for (int mf = 0; mf < 2; ++mf)
            #pragma unroll
            for (int nf = 0; nf < 2; ++nf)
                acc[mf][nf] = __builtin_amdgcn_mfma_f32_16x16x32_bf16(
                    af[mf], bfr[nf], acc[mf][nf], 0, 0, 0);
        ++cur; if (cur == 3) cur = 0;
    }

    const int colb = n0 + wc * 32;
    const int rowb = m0 + wr * 32 + (l >> 4) * 4;
    #pragma unroll
    for (int nf = 0; nf < 2; ++nf) {
        const int col = colb + nf * 16 + (l & 15);
        const float bias = bo[col];
        #pragma unroll
        for (int mf = 0; mf < 2; ++mf)
            #pragma unroll
            for (int r = 0; r < 4; ++r)
                out[(size_t)(rowb + mf * 16 + r) * 1024 + col] = acc[mf][nf][r] + bias;
    }
}

// ---------------------------------------------------------------------------
extern "C" void kernel_launch(void* const* d_in, const int* in_sizes, int n_in,
                              void* d_out, int out_size, void* d_ws, size_t ws_size,
                              hipStream_t stream) {
    const float* query = (const float*)d_in[0];
    const float* value = (const float*)d_in[1];
    const float* Wq    = (const float*)d_in[2];
    const float* bq    = (const float*)d_in[3];
    const float* Wk    = (const float*)d_in[4];
    const float* bk    = (const float*)d_in[5];
    const float* Wv    = (const float*)d_in[6];
    const float* bv    = (const float*)d_in[7];
    const float* Wo    = (const float*)d_in[8];
    const float* bo    = (const float*)d_in[9];
    const float* pds   = (const float*)d_in[10];
    float* out = (float*)d_out;

    // workspace layout (64 MiB total)
    char* ws = (char*)d_ws;
    u16* xb   = (u16*)(ws);                        // 16 MiB: query|value bf16
    u16* wbT  = (u16*)(ws + (16ull << 20));        //  6 MiB: Wq|Wk|Wv ^T bf16
    u16* woT  = (u16*)(ws + (22ull << 20));        //  2 MiB: Wo^T bf16
    u16* qkv  = (u16*)(ws + (24ull << 20));        // 24 MiB: q|k|(unused v)
    u16* vt   = (u16*)(ws + (48ull << 20));        //  8 MiB: v transposed [bn][h][s]
    u16* ctxb = (u16*)(ws + (56ull << 20));        //  8 MiB: context bf16

    cast_all_kernel<<<dim3(9216), 256, 0, stream>>>(
        query, value, Wq, Wk, Wv, Wo, xb, wbT, woT);
    gemm_qkv_kernel<<<dim3(N3 / 128, M_TOT / 128), 512, 0, stream>>>(
        xb, wbT, bq, bk, bv, pds, qkv, vt);
    attn_mfma_kernel<<<dim3(T_DIM / 128, 64), 512, 0, stream>>>(qkv, vt, ctxb);
    gemm_out_kernel<<<dim3(NH / 128, M_TOT / 64), 512, 0, stream>>>(ctxb, woT, bo, out);
}